// Round 1
// baseline (6018.411 us; speedup 1.0000x reference)
//
#include <hip/hip_runtime.h>

#define N_NODES 100000
#define DIM 128
#define NNZ_E 1600000

// ---------------------------------------------------------------------------
// Copy emb -> out[:, 0:128]  (out is [N, 384] row-major)
// ---------------------------------------------------------------------------
__global__ __launch_bounds__(256) void copy_emb_kernel(
    const float* __restrict__ emb, float* __restrict__ out)
{
    int tid = blockIdx.x * 256 + threadIdx.x;   // N*32 threads, one float4 each
    int n = tid >> 5, c = tid & 31;
    float4 v = ((const float4*)emb)[tid];
    *((float4*)(out + (size_t)n * 384) + c) = v;
}

// ---------------------------------------------------------------------------
// COO SpMM: side[row] += val * x[col]   (atomic scatter, 32 threads/edge)
// x addressed as float4 rows: stride xstride_f4, column offset xoff_f4
// ---------------------------------------------------------------------------
__global__ __launch_bounds__(256) void spmm_kernel(
    const int* __restrict__ rows, const int* __restrict__ cols,
    const float* __restrict__ vals, const float* __restrict__ x,
    int xstride_f4, int xoff_f4, float* __restrict__ side)
{
    int tid = blockIdx.x * 256 + threadIdx.x;
    int e = tid >> 5, c = tid & 31;
    int r  = rows[e];
    int cl = cols[e];
    float v = vals[e];
    float4 xv = *((const float4*)x + (size_t)cl * xstride_f4 + xoff_f4 + c);
    float* sp = side + (size_t)r * DIM + c * 4;
    unsafeAtomicAdd(sp + 0, v * xv.x);
    unsafeAtomicAdd(sp + 1, v * xv.y);
    unsafeAtomicAdd(sp + 2, v * xv.z);
    unsafeAtomicAdd(sp + 3, v * xv.w);
}

// ---------------------------------------------------------------------------
// Fused dense: y = leaky_relu((side+x)@W1^T + b1 + (side*x)@W2^T + b2)
//              x_out = y / max(||y||, 1e-12)    written to out[:, outoff:+128]
// W1,W2 staged in LDS (XOR-swizzled float4 rows, conflict-free b128 reads).
// 512 threads: j = t&127 (output col), g = t>>7 (node quad), 16 nodes/iter.
// ---------------------------------------------------------------------------
__global__ __launch_bounds__(512) void dense_kernel(
    const float* __restrict__ side, const float* __restrict__ x,
    int xstride_f4, int xoff_f4,
    const float* __restrict__ W1, const float* __restrict__ W2,
    const float* __restrict__ b1, const float* __restrict__ b2,
    float* __restrict__ out, int outoff)
{
    __shared__ float4 sW1[4096];   // 64 KB, W1[j][d4*4..] at [(j<<5)|(d4^(j&7))]
    __shared__ float4 sW2[4096];   // 64 KB
    __shared__ float4 sH1[512];    // 16 nodes x 32 f4 : side + x
    __shared__ float4 sH2[512];    // 16 nodes x 32 f4 : side * x
    __shared__ float  sY[2048];    // 16 nodes x 128
    __shared__ float  sNrm[16];

    int t = threadIdx.x;
    // ---- stage weights (once per block), swizzled for conflict-free reads
    for (int i = t; i < 4096; i += 512) {
        int j_ = i >> 5, d4_ = i & 31;
        int dst = (j_ << 5) | (d4_ ^ (j_ & 7));
        sW1[dst] = ((const float4*)W1)[i];
        sW2[dst] = ((const float4*)W2)[i];
    }
    int j = t & 127;        // output column
    int g = t >> 7;         // 0..3 -> local nodes g*4 .. g*4+3
    float bias = b1[j] + b2[j];
    __syncthreads();

    for (int grp = blockIdx.x; grp < (N_NODES / 16); grp += gridDim.x) {
        int b0 = grp * 16;
        // ---- stage h1 = side+x, h2 = side*x for 16 nodes (one f4 per thread)
        {
            int n = t >> 5, c = t & 31;
            float4 s  = ((const float4*)side)[(size_t)(b0 + n) * 32 + c];
            float4 xv = ((const float4*)x)[(size_t)(b0 + n) * xstride_f4 + xoff_f4 + c];
            sH1[n * 32 + c] = make_float4(s.x + xv.x, s.y + xv.y, s.z + xv.z, s.w + xv.w);
            sH2[n * 32 + c] = make_float4(s.x * xv.x, s.y * xv.y, s.z * xv.z, s.w * xv.w);
        }
        __syncthreads();

        // ---- two 128x128 dots, 4 nodes per thread
        float acc[4] = {0.f, 0.f, 0.f, 0.f};
        int wrow = j << 5, sw = j & 7;
        #pragma unroll 8
        for (int d4 = 0; d4 < 32; ++d4) {
            float4 w1 = sW1[wrow | (d4 ^ sw)];
            float4 w2 = sW2[wrow | (d4 ^ sw)];
            #pragma unroll
            for (int n = 0; n < 4; ++n) {
                float4 h1 = sH1[(g * 4 + n) * 32 + d4];
                float4 h2 = sH2[(g * 4 + n) * 32 + d4];
                acc[n] += w1.x * h1.x + w1.y * h1.y + w1.z * h1.z + w1.w * h1.w
                        + w2.x * h2.x + w2.y * h2.y + w2.z * h2.z + w2.w * h2.w;
            }
        }

        // ---- bias + leaky_relu, park in LDS for the norm reduction
        #pragma unroll
        for (int n = 0; n < 4; ++n) {
            float y = acc[n] + bias;
            y = (y >= 0.f) ? y : 0.01f * y;
            acc[n] = y;
            sY[(g * 4 + n) * 128 + j] = y;
        }
        __syncthreads();

        // ---- row L2 norm: 32 threads per node, shuffle-reduce width 32
        {
            int nn = t >> 5, l = t & 31;
            float s = 0.f;
            #pragma unroll
            for (int q = 0; q < 4; ++q) {
                float v = sY[nn * 128 + l + 32 * q];
                s += v * v;
            }
            #pragma unroll
            for (int m = 16; m >= 1; m >>= 1) s += __shfl_xor(s, m, 32);
            if (l == 0) sNrm[nn] = 1.0f / fmaxf(sqrtf(s), 1e-12f);
        }
        __syncthreads();

        // ---- scaled store (coalesced: consecutive j -> consecutive addresses)
        #pragma unroll
        for (int n = 0; n < 4; ++n) {
            out[(size_t)(b0 + g * 4 + n) * 384 + outoff + j] = acc[n] * sNrm[g * 4 + n];
        }
        // safe to overwrite sH next iter: everyone passed the post-sY sync,
        // and next iter's sY writes are fenced by the post-h-load sync.
    }
}

// ---------------------------------------------------------------------------
extern "C" void kernel_launch(void* const* d_in, const int* in_sizes, int n_in,
                              void* d_out, int out_size, void* d_ws, size_t ws_size,
                              hipStream_t stream)
{
    const int*   adj_row  = (const int*)d_in[0];
    const int*   adj_col  = (const int*)d_in[1];
    const float* adj_vals = (const float*)d_in[2];
    const float* emb      = (const float*)d_in[3];
    const float* W1_w     = (const float*)d_in[4];
    const float* W1_b     = (const float*)d_in[5];
    const float* W2_w     = (const float*)d_in[6];
    const float* W2_b     = (const float*)d_in[7];
    float* out  = (float*)d_out;
    float* side = (float*)d_ws;     // N*128 f32 = 51.2 MB scratch

    // out[:, 0:128] = emb
    copy_emb_kernel<<<N_NODES * 32 / 256, 256, 0, stream>>>(emb, out);

    for (int k = 0; k < 2; ++k) {
        hipMemsetAsync(side, 0, (size_t)N_NODES * DIM * sizeof(float), stream);

        const float* xsrc; int xs4, xo4;
        if (k == 0) { xsrc = emb; xs4 = 32; xo4 = 0;  }   // emb: [N,128]
        else        { xsrc = out; xs4 = 96; xo4 = 32; }   // prev layer in out[:,128:256]

        spmm_kernel<<<NNZ_E * 32 / 256, 256, 0, stream>>>(
            adj_row, adj_col, adj_vals, xsrc, xs4, xo4, side);

        dense_kernel<<<512, 512, 0, stream>>>(
            side, xsrc, xs4, xo4,
            W1_w + k * DIM * DIM, W2_w + k * DIM * DIM,
            W1_b + k * DIM,       W2_b + k * DIM,
            out, DIM * (k + 1));
    }
}

// Round 2
// 1024.987 us; speedup vs baseline: 5.8717x; 5.8717x over previous
//
#include <hip/hip_runtime.h>
#include <stdint.h>

#define N_NODES 100000
#define DIM 128
#define NNZ_E 1600000
#define SCAN_TILE 2048
#define N_TILES ((N_NODES + SCAN_TILE - 1) / SCAN_TILE)   // 49

// ---------------------------------------------------------------------------
// Copy emb -> out[:, 0:128]  (out is [N, 384] row-major)
// ---------------------------------------------------------------------------
__global__ __launch_bounds__(256) void copy_emb_kernel(
    const float* __restrict__ emb, float* __restrict__ out)
{
    int tid = blockIdx.x * 256 + threadIdx.x;   // N*32 threads, one float4 each
    int n = tid >> 5, c = tid & 31;
    float4 v = ((const float4*)emb)[tid];
    *((float4*)(out + (size_t)n * 384) + c) = v;
}

// ---------------------------------------------------------------------------
// CSR build: histogram -> 3-pass exclusive scan -> scatter (col,val) pairs
// ---------------------------------------------------------------------------
__global__ __launch_bounds__(256) void hist_kernel(
    const int* __restrict__ rows, int* __restrict__ cnt)
{
    int e = blockIdx.x * 256 + threadIdx.x;
    atomicAdd(&cnt[rows[e]], 1);
}

__global__ __launch_bounds__(256) void scan_pass_a(
    const int* __restrict__ cnt, int* __restrict__ tile_sums)
{
    __shared__ int sdata[256];
    int base = blockIdx.x * SCAN_TILE + threadIdx.x * 8;
    int s = 0;
    #pragma unroll
    for (int q = 0; q < 8; ++q) {
        int i = base + q;
        s += (i < N_NODES) ? cnt[i] : 0;
    }
    sdata[threadIdx.x] = s;
    __syncthreads();
    for (int off = 128; off >= 1; off >>= 1) {
        if (threadIdx.x < off) sdata[threadIdx.x] += sdata[threadIdx.x + off];
        __syncthreads();
    }
    if (threadIdx.x == 0) tile_sums[blockIdx.x] = sdata[0];
}

__global__ void scan_pass_b(int* __restrict__ tile_sums)
{
    if (threadIdx.x == 0 && blockIdx.x == 0) {
        int acc = 0;
        for (int i = 0; i < N_TILES; ++i) {
            int t = tile_sums[i]; tile_sums[i] = acc; acc += t;
        }
    }
}

__global__ __launch_bounds__(256) void scan_pass_c(
    const int* __restrict__ cnt, const int* __restrict__ tile_offs,
    int* __restrict__ row_ptr)
{
    __shared__ int spart[256];
    int t = threadIdx.x;
    int base = blockIdx.x * SCAN_TILE + t * 8;
    int loc[8];
    int s = 0;
    #pragma unroll
    for (int q = 0; q < 8; ++q) {
        int i = base + q;
        int c = (i < N_NODES) ? cnt[i] : 0;
        loc[q] = s; s += c;
    }
    spart[t] = s;
    __syncthreads();
    // Hillis-Steele inclusive scan over the 256 per-thread sums
    for (int off = 1; off < 256; off <<= 1) {
        int v = (t >= off) ? spart[t - off] : 0;
        __syncthreads();
        spart[t] += v;
        __syncthreads();
    }
    int exoff = tile_offs[blockIdx.x] + spart[t] - s;   // exclusive offset
    #pragma unroll
    for (int q = 0; q < 8; ++q) {
        int i = base + q;
        if (i <= N_NODES) row_ptr[i] = exoff + loc[q];
    }
}

__global__ __launch_bounds__(256) void scatter_kernel(
    const int* __restrict__ rows, const int* __restrict__ cols,
    const float* __restrict__ vals, const int* __restrict__ row_ptr,
    int* __restrict__ fill, int2* __restrict__ edges)
{
    int e = blockIdx.x * 256 + threadIdx.x;
    int r = rows[e];
    int pos = row_ptr[r] + atomicAdd(&fill[r], 1);
    edges[pos] = make_int2(cols[e], __float_as_int(vals[e]));
}

// ---------------------------------------------------------------------------
// Gather SpMM: one 64-lane wave per output row; float2 per lane; no atomics.
// ---------------------------------------------------------------------------
__global__ __launch_bounds__(256) void spmm_gather_kernel(
    const int* __restrict__ row_ptr, const int2* __restrict__ edges,
    const float* __restrict__ x, int xs2, int xo2,
    float* __restrict__ side)
{
    int w = blockIdx.x * 4 + (threadIdx.x >> 6);   // row index
    int lane = threadIdx.x & 63;
    int beg = row_ptr[w], end = row_ptr[w + 1];
    const float2* xp = (const float2*)x;
    float ax = 0.f, ay = 0.f;
    int i = beg;
    for (; i + 1 < end; i += 2) {                  // 2 gathers in flight
        int2 c0 = edges[i];
        int2 c1 = edges[i + 1];
        float2 x0 = xp[(size_t)c0.x * xs2 + xo2 + lane];
        float2 x1 = xp[(size_t)c1.x * xs2 + xo2 + lane];
        float v0 = __int_as_float(c0.y), v1 = __int_as_float(c1.y);
        ax += v0 * x0.x; ay += v0 * x0.y;
        ax += v1 * x1.x; ay += v1 * x1.y;
    }
    if (i < end) {
        int2 c0 = edges[i];
        float2 x0 = xp[(size_t)c0.x * xs2 + xo2 + lane];
        float v0 = __int_as_float(c0.y);
        ax += v0 * x0.x; ay += v0 * x0.y;
    }
    ((float2*)side)[(size_t)w * 64 + lane] = make_float2(ax, ay);
}

// ---------------------------------------------------------------------------
// Fallback atomic SpMM (only if ws_size too small for CSR scratch)
// ---------------------------------------------------------------------------
__global__ __launch_bounds__(256) void spmm_atomic_kernel(
    const int* __restrict__ rows, const int* __restrict__ cols,
    const float* __restrict__ vals, const float* __restrict__ x,
    int xstride_f4, int xoff_f4, float* __restrict__ side)
{
    int tid = blockIdx.x * 256 + threadIdx.x;
    int e = tid >> 5, c = tid & 31;
    int r  = rows[e];
    int cl = cols[e];
    float v = vals[e];
    float4 xv = *((const float4*)x + (size_t)cl * xstride_f4 + xoff_f4 + c);
    float* sp = side + (size_t)r * DIM + c * 4;
    unsafeAtomicAdd(sp + 0, v * xv.x);
    unsafeAtomicAdd(sp + 1, v * xv.y);
    unsafeAtomicAdd(sp + 2, v * xv.z);
    unsafeAtomicAdd(sp + 3, v * xv.w);
}

// ---------------------------------------------------------------------------
// Fused dense: y = leaky_relu((side+x)@W1^T + b1 + (side*x)@W2^T + b2)
//              x_out = y / max(||y||, 1e-12)    written to out[:, outoff:+128]
// ---------------------------------------------------------------------------
__global__ __launch_bounds__(512) void dense_kernel(
    const float* __restrict__ side, const float* __restrict__ x,
    int xstride_f4, int xoff_f4,
    const float* __restrict__ W1, const float* __restrict__ W2,
    const float* __restrict__ b1, const float* __restrict__ b2,
    float* __restrict__ out, int outoff)
{
    __shared__ float4 sW1[4096];   // 64 KB, W1[j][d4*4..] at [(j<<5)|(d4^(j&7))]
    __shared__ float4 sW2[4096];   // 64 KB
    __shared__ float4 sH1[512];    // 16 nodes x 32 f4 : side + x
    __shared__ float4 sH2[512];    // 16 nodes x 32 f4 : side * x
    __shared__ float  sY[2048];    // 16 nodes x 128
    __shared__ float  sNrm[16];

    int t = threadIdx.x;
    for (int i = t; i < 4096; i += 512) {
        int j_ = i >> 5, d4_ = i & 31;
        int dst = (j_ << 5) | (d4_ ^ (j_ & 7));
        sW1[dst] = ((const float4*)W1)[i];
        sW2[dst] = ((const float4*)W2)[i];
    }
    int j = t & 127;        // output column
    int g = t >> 7;         // 0..3 -> local nodes g*4 .. g*4+3
    float bias = b1[j] + b2[j];
    __syncthreads();

    for (int grp = blockIdx.x; grp < (N_NODES / 16); grp += gridDim.x) {
        int b0 = grp * 16;
        {
            int n = t >> 5, c = t & 31;
            float4 s  = ((const float4*)side)[(size_t)(b0 + n) * 32 + c];
            float4 xv = ((const float4*)x)[(size_t)(b0 + n) * xstride_f4 + xoff_f4 + c];
            sH1[n * 32 + c] = make_float4(s.x + xv.x, s.y + xv.y, s.z + xv.z, s.w + xv.w);
            sH2[n * 32 + c] = make_float4(s.x * xv.x, s.y * xv.y, s.z * xv.z, s.w * xv.w);
        }
        __syncthreads();

        float acc[4] = {0.f, 0.f, 0.f, 0.f};
        int wrow = j << 5, sw = j & 7;
        #pragma unroll 8
        for (int d4 = 0; d4 < 32; ++d4) {
            float4 w1 = sW1[wrow | (d4 ^ sw)];
            float4 w2 = sW2[wrow | (d4 ^ sw)];
            #pragma unroll
            for (int n = 0; n < 4; ++n) {
                float4 h1 = sH1[(g * 4 + n) * 32 + d4];
                float4 h2 = sH2[(g * 4 + n) * 32 + d4];
                acc[n] += w1.x * h1.x + w1.y * h1.y + w1.z * h1.z + w1.w * h1.w
                        + w2.x * h2.x + w2.y * h2.y + w2.z * h2.z + w2.w * h2.w;
            }
        }

        #pragma unroll
        for (int n = 0; n < 4; ++n) {
            float y = acc[n] + bias;
            y = (y >= 0.f) ? y : 0.01f * y;
            acc[n] = y;
            sY[(g * 4 + n) * 128 + j] = y;
        }
        __syncthreads();

        {
            int nn = t >> 5, l = t & 31;
            float s = 0.f;
            #pragma unroll
            for (int q = 0; q < 4; ++q) {
                float v = sY[nn * 128 + l + 32 * q];
                s += v * v;
            }
            #pragma unroll
            for (int m = 16; m >= 1; m >>= 1) s += __shfl_xor(s, m, 32);
            if (l == 0) sNrm[nn] = 1.0f / fmaxf(sqrtf(s), 1e-12f);
        }
        __syncthreads();

        #pragma unroll
        for (int n = 0; n < 4; ++n) {
            out[(size_t)(b0 + g * 4 + n) * 384 + outoff + j] = acc[n] * sNrm[g * 4 + n];
        }
    }
}

// ---------------------------------------------------------------------------
extern "C" void kernel_launch(void* const* d_in, const int* in_sizes, int n_in,
                              void* d_out, int out_size, void* d_ws, size_t ws_size,
                              hipStream_t stream)
{
    const int*   adj_row  = (const int*)d_in[0];
    const int*   adj_col  = (const int*)d_in[1];
    const float* adj_vals = (const float*)d_in[2];
    const float* emb      = (const float*)d_in[3];
    const float* W1_w     = (const float*)d_in[4];
    const float* W1_b     = (const float*)d_in[5];
    const float* W2_w     = (const float*)d_in[6];
    const float* W2_b     = (const float*)d_in[7];
    float* out = (float*)d_out;

    // ---- workspace layout (16B-aligned offsets) ----
    uint8_t* w = (uint8_t*)d_ws;
    const size_t SIDE_B  = (size_t)N_NODES * DIM * sizeof(float);       // 51,200,000
    const size_t EDGE_B  = (size_t)NNZ_E * sizeof(int2);                // 12,800,000
    float* side   = (float*)w;
    int2*  edges  = (int2*)(w + SIDE_B);
    int*   row_ptr= (int*) (w + SIDE_B + EDGE_B);                       // N+1 ints
    int*   cnt    = (int*) (w + SIDE_B + EDGE_B + 400016);              // N ints
    int*   fill   = (int*) (w + SIDE_B + EDGE_B + 800016);              // N ints
    int*   tsums  = (int*) (w + SIDE_B + EDGE_B + 1200016);             // N_TILES ints
    const size_t NEED = SIDE_B + EDGE_B + 1200016 + 4096;
    const bool use_csr = (ws_size >= NEED);   // host-constant across calls

    // out[:, 0:128] = emb
    copy_emb_kernel<<<N_NODES * 32 / 256, 256, 0, stream>>>(emb, out);

    if (use_csr) {
        // ---- build CSR once per call ----
        hipMemsetAsync(cnt,  0, (size_t)N_NODES * sizeof(int), stream);
        hipMemsetAsync(fill, 0, (size_t)N_NODES * sizeof(int), stream);
        hist_kernel<<<NNZ_E / 256, 256, 0, stream>>>(adj_row, cnt);
        scan_pass_a<<<N_TILES, 256, 0, stream>>>(cnt, tsums);
        scan_pass_b<<<1, 64, 0, stream>>>(tsums);
        scan_pass_c<<<N_TILES, 256, 0, stream>>>(cnt, tsums, row_ptr);
        scatter_kernel<<<NNZ_E / 256, 256, 0, stream>>>(
            adj_row, adj_col, adj_vals, row_ptr, fill, edges);
    }

    for (int k = 0; k < 2; ++k) {
        const float* xsrc; int xs4, xo4;
        if (k == 0) { xsrc = emb; xs4 = 32; xo4 = 0;  }   // emb: [N,128]
        else        { xsrc = out; xs4 = 96; xo4 = 32; }   // prev layer in out[:,128:256]

        if (use_csr) {
            spmm_gather_kernel<<<N_NODES / 4, 256, 0, stream>>>(
                row_ptr, edges, xsrc, xs4 * 2, xo4 * 2, side);
        } else {
            hipMemsetAsync(side, 0, SIDE_B, stream);
            spmm_atomic_kernel<<<NNZ_E * 32 / 256, 256, 0, stream>>>(
                adj_row, adj_col, adj_vals, xsrc, xs4, xo4, side);
        }

        dense_kernel<<<512, 512, 0, stream>>>(
            side, xsrc, xs4, xo4,
            W1_w + k * DIM * DIM, W2_w + k * DIM * DIM,
            W1_b + k * DIM,       W2_b + k * DIM,
            out, DIM * (k + 1));
    }
}

// Round 3
// 634.405 us; speedup vs baseline: 9.4867x; 1.6157x over previous
//
#include <hip/hip_runtime.h>
#include <stdint.h>

#define N_NODES 100000
#define NPAD    100032
#define DIM 128
#define NNZ_E 1600000
#define SCAN_TILE 2048
#define N_TILES ((N_NODES + SCAN_TILE - 1) / SCAN_TILE)   // 49

typedef float f32x4  __attribute__((ext_vector_type(4)));
typedef short bf16x8 __attribute__((ext_vector_type(8)));

union B8 { uint4 q; unsigned u[4]; bf16x8 v; };

__device__ __forceinline__ unsigned short f2bs(float f) {   // fp32 -> bf16 RNE
    unsigned u = __builtin_bit_cast(unsigned, f);
    u = (u + 0x7fffu + ((u >> 16) & 1u)) >> 16;
    return (unsigned short)u;
}
__device__ __forceinline__ unsigned pk2(float a, float b) {
    return (unsigned)f2bs(a) | ((unsigned)f2bs(b) << 16);
}
#define UNPK(u32, flo, fhi) { flo = __builtin_bit_cast(float, (unsigned)((u32) << 16)); \
                              fhi = __builtin_bit_cast(float, (unsigned)((u32) & 0xffff0000u)); }

// ---------------------------------------------------------------------------
// emb -> out[:,0:128] fp32  AND  xbuf bf16
// ---------------------------------------------------------------------------
__global__ __launch_bounds__(256) void copy_emb_kernel(
    const float* __restrict__ emb, float* __restrict__ out,
    unsigned* __restrict__ xbuf)
{
    int tid = blockIdx.x * 256 + threadIdx.x;   // N*32 threads, one float4 each
    int n = tid >> 5, c = tid & 31;
    float4 v = ((const float4*)emb)[tid];
    *((float4*)(out + (size_t)n * 384) + c) = v;
    ((uint2*)xbuf)[(size_t)n * 32 + c] = make_uint2(pk2(v.x, v.y), pk2(v.z, v.w));
}

// ---------------------------------------------------------------------------
// W fp32 -> bf16 (both layers, both matrices). 8192 float4 per matrix set.
// ---------------------------------------------------------------------------
__global__ __launch_bounds__(256) void wconv_kernel(
    const float* __restrict__ W1, const float* __restrict__ W2,
    unsigned* __restrict__ w1b, unsigned* __restrict__ w2b)
{
    int tid = blockIdx.x * 256 + threadIdx.x;   // 0..8191
    float4 a = ((const float4*)W1)[tid];
    float4 b = ((const float4*)W2)[tid];
    ((uint2*)w1b)[tid] = make_uint2(pk2(a.x, a.y), pk2(a.z, a.w));
    ((uint2*)w2b)[tid] = make_uint2(pk2(b.x, b.y), pk2(b.z, b.w));
}

// ---------------------------------------------------------------------------
// CSR build: histogram -> 3-pass exclusive scan -> scatter (col,val) pairs
// ---------------------------------------------------------------------------
__global__ __launch_bounds__(256) void hist_kernel(
    const int* __restrict__ rows, int* __restrict__ cnt)
{
    int e = blockIdx.x * 256 + threadIdx.x;
    atomicAdd(&cnt[rows[e]], 1);
}

__global__ __launch_bounds__(256) void scan_pass_a(
    const int* __restrict__ cnt, int* __restrict__ tile_sums)
{
    __shared__ int sdata[256];
    int base = blockIdx.x * SCAN_TILE + threadIdx.x * 8;
    int s = 0;
    #pragma unroll
    for (int q = 0; q < 8; ++q) {
        int i = base + q;
        s += (i < N_NODES) ? cnt[i] : 0;
    }
    sdata[threadIdx.x] = s;
    __syncthreads();
    for (int off = 128; off >= 1; off >>= 1) {
        if (threadIdx.x < off) sdata[threadIdx.x] += sdata[threadIdx.x + off];
        __syncthreads();
    }
    if (threadIdx.x == 0) tile_sums[blockIdx.x] = sdata[0];
}

__global__ void scan_pass_b(int* __restrict__ tile_sums)
{
    if (threadIdx.x == 0 && blockIdx.x == 0) {
        int acc = 0;
        for (int i = 0; i < N_TILES; ++i) {
            int t = tile_sums[i]; tile_sums[i] = acc; acc += t;
        }
    }
}

__global__ __launch_bounds__(256) void scan_pass_c(
    const int* __restrict__ cnt, const int* __restrict__ tile_offs,
    int* __restrict__ row_ptr)
{
    __shared__ int spart[256];
    int t = threadIdx.x;
    int base = blockIdx.x * SCAN_TILE + t * 8;
    int loc[8];
    int s = 0;
    #pragma unroll
    for (int q = 0; q < 8; ++q) {
        int i = base + q;
        int c = (i < N_NODES) ? cnt[i] : 0;
        loc[q] = s; s += c;
    }
    spart[t] = s;
    __syncthreads();
    for (int off = 1; off < 256; off <<= 1) {
        int v = (t >= off) ? spart[t - off] : 0;
        __syncthreads();
        spart[t] += v;
        __syncthreads();
    }
    int exoff = tile_offs[blockIdx.x] + spart[t] - s;
    #pragma unroll
    for (int q = 0; q < 8; ++q) {
        int i = base + q;
        if (i <= N_NODES) row_ptr[i] = exoff + loc[q];
    }
}

__global__ __launch_bounds__(256) void scatter_kernel(
    const int* __restrict__ rows, const int* __restrict__ cols,
    const float* __restrict__ vals, const int* __restrict__ row_ptr,
    int* __restrict__ fill, int2* __restrict__ edges)
{
    int e = blockIdx.x * 256 + threadIdx.x;
    int r = rows[e];
    int pos = row_ptr[r] + atomicAdd(&fill[r], 1);
    edges[pos] = make_int2(cols[e], __float_as_int(vals[e]));
}

// ---------------------------------------------------------------------------
// Gather SpMM (bf16 x, bf16 side): one wave per row; 1 uint (2 bf16) per lane.
// ---------------------------------------------------------------------------
__global__ __launch_bounds__(256) void spmm_gather_bf16(
    const int* __restrict__ row_ptr, const int2* __restrict__ edges,
    const unsigned* __restrict__ xb, unsigned* __restrict__ sideb)
{
    int row  = blockIdx.x * 4 + (threadIdx.x >> 6);
    int lane = threadIdx.x & 63;
    int beg = row_ptr[row], end = row_ptr[row + 1];
    float ax = 0.f, ay = 0.f;
    int i = beg;
    for (; i + 3 < end; i += 4) {               // 4 gathers in flight
        int2 e0 = edges[i], e1 = edges[i + 1], e2 = edges[i + 2], e3 = edges[i + 3];
        unsigned u0 = xb[(size_t)e0.x * 64 + lane];
        unsigned u1 = xb[(size_t)e1.x * 64 + lane];
        unsigned u2 = xb[(size_t)e2.x * 64 + lane];
        unsigned u3 = xb[(size_t)e3.x * 64 + lane];
        float v0 = __int_as_float(e0.y), v1 = __int_as_float(e1.y);
        float v2 = __int_as_float(e2.y), v3 = __int_as_float(e3.y);
        float lo, hi;
        UNPK(u0, lo, hi); ax += v0 * lo; ay += v0 * hi;
        UNPK(u1, lo, hi); ax += v1 * lo; ay += v1 * hi;
        UNPK(u2, lo, hi); ax += v2 * lo; ay += v2 * hi;
        UNPK(u3, lo, hi); ax += v3 * lo; ay += v3 * hi;
    }
    for (; i < end; ++i) {
        int2 e = edges[i];
        unsigned u = xb[(size_t)e.x * 64 + lane];
        float v = __int_as_float(e.y), lo, hi;
        UNPK(u, lo, hi); ax += v * lo; ay += v * hi;
    }
    sideb[(size_t)row * 64 + lane] = pk2(ax, ay);
}

// ---------------------------------------------------------------------------
// MFMA dense: Y = leaky_relu((side+x)@W1^T + (side*x)@W2^T + b1 + b2), L2-norm
// rows, write fp32 to out[:, outoff:+128]; if write_x, also rewrite xbuf (bf16)
// in place (safe: per-block row-exclusive, stores after the barrier).
// Block = 4 waves; wave w owns cols [w*32, w*32+32), 64 nodes per block.
// W fragments live in registers (no LDS). A-frags built from global bf16.
// ---------------------------------------------------------------------------
__global__ __launch_bounds__(256) void dense_mfma_kernel(
    const unsigned* __restrict__ sideb, unsigned* __restrict__ xbuf,
    const unsigned* __restrict__ w1b, const unsigned* __restrict__ w2b,
    const float* __restrict__ b1, const float* __restrict__ b2,
    float* __restrict__ out, int outoff, int write_x)
{
    __shared__ float sPart[256];          // [wave][64 local nodes]
    const int t = threadIdx.x;
    const int wave = t >> 6, lane = t & 63;
    const int q = lane >> 4, r = lane & 15;
    const int colbase = wave * 32;

    // ---- B-operand fragments: lane holds W[j = colbase+nt*16+r][kk*32+q*8 ..+8)
    bf16x8 Wf[2][2][4];                   // [mat][nt][kk]
    {
        const uint4* w1p = (const uint4*)w1b;
        const uint4* w2p = (const uint4*)w2b;
        #pragma unroll
        for (int nt = 0; nt < 2; ++nt) {
            int j = colbase + nt * 16 + r;
            #pragma unroll
            for (int kk = 0; kk < 4; ++kk) {
                B8 a, b;
                a.q = w1p[j * 16 + kk * 4 + q];
                b.q = w2p[j * 16 + kk * 4 + q];
                Wf[0][nt][kk] = a.v;
                Wf[1][nt][kk] = b.v;
            }
        }
    }
    const float bias0 = b1[colbase + r]      + b2[colbase + r];
    const float bias1 = b1[colbase + 16 + r] + b2[colbase + 16 + r];

    const int base = blockIdx.x * 64;
    f32x4 acc[4][2];
    #pragma unroll
    for (int mt = 0; mt < 4; ++mt) {
        acc[mt][0] = (f32x4){0.f, 0.f, 0.f, 0.f};
        acc[mt][1] = (f32x4){0.f, 0.f, 0.f, 0.f};
    }

    #pragma unroll
    for (int mt = 0; mt < 4; ++mt) {
        const size_t node = (size_t)(base + mt * 16 + r);
        const uint4* sp = (const uint4*)sideb + node * 16 + q;
        const uint4* xp = (const uint4*)xbuf  + node * 16 + q;
        #pragma unroll
        for (int kk = 0; kk < 4; ++kk) {
            uint4 sv = sp[kk * 4];
            uint4 xv = xp[kk * 4];
            float s0,s1,s2,s3,s4,s5,s6,s7;
            float x0,x1,x2,x3,x4,x5,x6,x7;
            UNPK(sv.x, s0, s1); UNPK(sv.y, s2, s3);
            UNPK(sv.z, s4, s5); UNPK(sv.w, s6, s7);
            UNPK(xv.x, x0, x1); UNPK(xv.y, x2, x3);
            UNPK(xv.z, x4, x5); UNPK(xv.w, x6, x7);
            B8 a1, a2;
            a1.u[0] = pk2(s0 + x0, s1 + x1);
            a1.u[1] = pk2(s2 + x2, s3 + x3);
            a1.u[2] = pk2(s4 + x4, s5 + x5);
            a1.u[3] = pk2(s6 + x6, s7 + x7);
            a2.u[0] = pk2(s0 * x0, s1 * x1);
            a2.u[1] = pk2(s2 * x2, s3 * x3);
            a2.u[2] = pk2(s4 * x4, s5 * x5);
            a2.u[3] = pk2(s6 * x6, s7 * x7);
            acc[mt][0] = __builtin_amdgcn_mfma_f32_16x16x32_bf16(a1.v, Wf[0][0][kk], acc[mt][0], 0, 0, 0);
            acc[mt][0] = __builtin_amdgcn_mfma_f32_16x16x32_bf16(a2.v, Wf[1][0][kk], acc[mt][0], 0, 0, 0);
            acc[mt][1] = __builtin_amdgcn_mfma_f32_16x16x32_bf16(a1.v, Wf[0][1][kk], acc[mt][1], 0, 0, 0);
            acc[mt][1] = __builtin_amdgcn_mfma_f32_16x16x32_bf16(a2.v, Wf[1][1][kk], acc[mt][1], 0, 0, 0);
        }
    }

    // ---- bias + leaky_relu; per-node partial square-sums (this wave's 32 cols)
    // C/D layout: col = lane&15, row = q*4 + reg  -> node = base+mt*16+q*4+i
    #pragma unroll
    for (int mt = 0; mt < 4; ++mt) {
        #pragma unroll
        for (int i = 0; i < 4; ++i) {
            float y0 = acc[mt][0][i] + bias0; y0 = (y0 >= 0.f) ? y0 : 0.01f * y0;
            float y1 = acc[mt][1][i] + bias1; y1 = (y1 >= 0.f) ? y1 : 0.01f * y1;
            acc[mt][0][i] = y0; acc[mt][1][i] = y1;
            float s = y0 * y0 + y1 * y1;
            s += __shfl_xor(s, 1); s += __shfl_xor(s, 2);
            s += __shfl_xor(s, 4); s += __shfl_xor(s, 8);   // reduce 16 lanes (same q)
            if (r == 0) sPart[wave * 64 + mt * 16 + q * 4 + i] = s;
        }
    }
    __syncthreads();

    // ---- total norm, scale, store
    #pragma unroll
    for (int mt = 0; mt < 4; ++mt) {
        #pragma unroll
        for (int i = 0; i < 4; ++i) {
            int nl = mt * 16 + q * 4 + i;
            float tot = sPart[nl] + sPart[64 + nl] + sPart[128 + nl] + sPart[192 + nl];
            float inv = 1.0f / fmaxf(sqrtf(tot), 1e-12f);
            int node = base + nl;
            if (node < N_NODES) {
                float y0 = acc[mt][0][i] * inv;
                float y1 = acc[mt][1][i] * inv;
                out[(size_t)node * 384 + outoff + colbase + r]      = y0;
                out[(size_t)node * 384 + outoff + colbase + 16 + r] = y1;
                if (write_x) {
                    ((unsigned short*)xbuf)[(size_t)node * 128 + colbase + r]      = f2bs(y0);
                    ((unsigned short*)xbuf)[(size_t)node * 128 + colbase + 16 + r] = f2bs(y1);
                }
            }
        }
    }
}

// ---------------------------------------------------------------------------
extern "C" void kernel_launch(void* const* d_in, const int* in_sizes, int n_in,
                              void* d_out, int out_size, void* d_ws, size_t ws_size,
                              hipStream_t stream)
{
    const int*   adj_row  = (const int*)d_in[0];
    const int*   adj_col  = (const int*)d_in[1];
    const float* adj_vals = (const float*)d_in[2];
    const float* emb      = (const float*)d_in[3];
    const float* W1_w     = (const float*)d_in[4];
    const float* W1_b     = (const float*)d_in[5];
    const float* W2_w     = (const float*)d_in[6];
    const float* W2_b     = (const float*)d_in[7];
    float* out = (float*)d_out;

    // ---- workspace layout (bytes; all 16B-aligned). Total ~64.95 MB.
    uint8_t* w = (uint8_t*)d_ws;
    unsigned* xbuf    = (unsigned*)(w);                 // NPAD*128 bf16 = 25,608,192 B
    unsigned* sideb   = (unsigned*)(w + 25608192);      // NPAD*128 bf16
    int2*     edges   = (int2*)    (w + 51216384);      // NNZ*8 = 12,800,000 B
    unsigned* w1b     = (unsigned*)(w + 64016384);      // 2*128*128 bf16 = 65,536 B
    unsigned* w2b     = (unsigned*)(w + 64081920);      // 65,536 B
    int*      row_ptr = (int*)     (w + 64147456);      // (N+1)*4
    int*      cnt     = (int*)     (w + 64547472);      // N*4 (reused as fill)
    int*      tsums   = (int*)     (w + 64947488);      // N_TILES*4

    wconv_kernel<<<32, 256, 0, stream>>>(W1_w, W2_w, w1b, w2b);
    copy_emb_kernel<<<N_NODES * 32 / 256, 256, 0, stream>>>(emb, out, xbuf);
    // zero the 32 padding rows (read by dense A-loads, must be 0)
    hipMemsetAsync(xbuf  + (size_t)N_NODES * 64, 0, (NPAD - N_NODES) * 256, stream);
    hipMemsetAsync(sideb + (size_t)N_NODES * 64, 0, (NPAD - N_NODES) * 256, stream);

    // ---- CSR build
    hipMemsetAsync(cnt, 0, (size_t)N_NODES * sizeof(int), stream);
    hist_kernel<<<NNZ_E / 256, 256, 0, stream>>>(adj_row, cnt);
    scan_pass_a<<<N_TILES, 256, 0, stream>>>(cnt, tsums);
    scan_pass_b<<<1, 64, 0, stream>>>(tsums);
    scan_pass_c<<<N_TILES, 256, 0, stream>>>(cnt, tsums, row_ptr);
    hipMemsetAsync(cnt, 0, (size_t)N_NODES * sizeof(int), stream);  // now the fill array
    scatter_kernel<<<NNZ_E / 256, 256, 0, stream>>>(
        adj_row, adj_col, adj_vals, row_ptr, cnt, edges);

    for (int k = 0; k < 2; ++k) {
        spmm_gather_bf16<<<N_NODES / 4, 256, 0, stream>>>(row_ptr, edges, xbuf, sideb);
        dense_mfma_kernel<<<NPAD / 64, 256, 0, stream>>>(
            sideb, xbuf, w1b + k * 8192, w2b + k * 8192,
            W1_b + k * DIM, W2_b + k * DIM,
            out, DIM * (k + 1), (k == 0) ? 1 : 0);
    }
}